// Round 2
// baseline (89.715 us; speedup 1.0000x reference)
//
#include <hip/hip_runtime.h>
#include <hip/hip_cooperative_groups.h>

namespace cg = cooperative_groups;

// Reference collapses (verified round 1, absmax=0.0): nn_idx[0]==0 always
// (self-distance 0 is the first minimum of dist row 0), so
// neighbor_feat = relu(features[b,0,:]) and the N^2 distance matrix is dead.
//
// Per batch b:
//   f       = relu(features[b])            [N,C]
//   r0      = f[0,:]                       [C]
//   gamma_i = max_j exp(f_ij - r0_j) * (f_ij / max_j f_ij)
//   out_i   = gamma_i / ||gamma||_2
//
// Single cooperative kernel: phase 1 computes gamma + per-block sum of
// squares (plain store, no atomics -> no memset node); grid.sync(); phase 2
// every block redundantly reduces its batch's 32 partials and normalizes.
// 64 blocks << 256 CUs so cooperative co-residency is trivially satisfied.

constexpr int kN = 8192;
constexpr int kC = 32;
constexpr int kBlock = 256;
constexpr int kBlocksPerBatch = kN / kBlock;  // 32

__global__ __launch_bounds__(kBlock) void detection_kernel(
    const float* __restrict__ feats, float* __restrict__ out,
    float* __restrict__ partials) {
  cg::grid_group grid = cg::this_grid();

  const int blk = blockIdx.x;
  const int b = blk / kBlocksPerBatch;      // 32 blocks per batch
  const int row = (blk % kBlocksPerBatch) * kBlock + threadIdx.x;
  const float* fb = feats + (size_t)b * kN * kC;

  // Load this row's 32 features (8x float4, contiguous) and row 0's.
  const float4* fr = reinterpret_cast<const float4*>(fb + (size_t)row * kC);
  const float4* f0 = reinterpret_cast<const float4*>(fb);

  float v[kC], r0[kC];
#pragma unroll
  for (int q = 0; q < kC / 4; ++q) {
    float4 t = fr[q];
    v[4 * q + 0] = fmaxf(t.x, 0.f);
    v[4 * q + 1] = fmaxf(t.y, 0.f);
    v[4 * q + 2] = fmaxf(t.z, 0.f);
    v[4 * q + 3] = fmaxf(t.w, 0.f);
    float4 z = f0[q];  // block-uniform, cache-resident
    r0[4 * q + 0] = fmaxf(z.x, 0.f);
    r0[4 * q + 1] = fmaxf(z.y, 0.f);
    r0[4 * q + 2] = fmaxf(z.z, 0.f);
    r0[4 * q + 3] = fmaxf(z.w, 0.f);
  }

  float m = 0.f;
#pragma unroll
  for (int j = 0; j < kC; ++j) m = fmaxf(m, v[j]);
  const float inv_m = 1.0f / m;  // m>0 w.p. 1 - 2^-32

  float g = 0.f;
#pragma unroll
  for (int j = 0; j < kC; ++j)
    g = fmaxf(g, __expf(v[j] - r0[j]) * (v[j] * inv_m));

  // Block-level sum of g^2: wave shuffle reduce, then 4 wave partials in LDS.
  float ss = g * g;
#pragma unroll
  for (int off = 32; off > 0; off >>= 1) ss += __shfl_down(ss, off, 64);
  __shared__ float s_wave[kBlock / 64];
  if ((threadIdx.x & 63) == 0) s_wave[threadIdx.x >> 6] = ss;
  __syncthreads();
  if (threadIdx.x == 0)
    partials[blk] = s_wave[0] + s_wave[1] + s_wave[2] + s_wave[3];

  grid.sync();  // partials visible grid-wide

  // Every block redundantly sums its batch's 32 partials (lanes 0..31).
  __shared__ float s_inv;
  if (threadIdx.x < 64) {
    float p = (threadIdx.x < kBlocksPerBatch)
                  ? partials[b * kBlocksPerBatch + threadIdx.x]
                  : 0.f;
#pragma unroll
    for (int off = 16; off > 0; off >>= 1) p += __shfl_down(p, off, 64);
    if (threadIdx.x == 0) s_inv = 1.0f / sqrtf(p);
  }
  __syncthreads();

  out[(size_t)b * kN + row] = g * s_inv;
}

extern "C" void kernel_launch(void* const* d_in, const int* in_sizes, int n_in,
                              void* d_out, int out_size, void* d_ws,
                              size_t ws_size, hipStream_t stream) {
  // d_in[0]=coords (unused, dead code), d_in[1]=features [B,N,C] f32,
  // d_in[2]=len_batch (unused).
  const float* feats = (const float*)d_in[1];
  float* out = (float*)d_out;
  float* partials = (float*)d_ws;  // 64 floats; written before read each call

  const int B = out_size / kN;  // 2
  dim3 grid(B * kBlocksPerBatch);  // 64 blocks
  dim3 block(kBlock);

  void* args[] = {(void*)&feats, (void*)&out, (void*)&partials};
  hipLaunchCooperativeKernel((const void*)detection_kernel, grid, block, args,
                             0, stream);
}

// Round 3
// 60.574 us; speedup vs baseline: 1.4811x; 1.4811x over previous
//
#include <hip/hip_runtime.h>

// Reference collapses (verified rounds 1-2, absmax=0.0): nn_idx[0]==0 always
// (self-distance 0 is the first minimum of dist row 0), so
// neighbor_feat = relu(features[b,0,:]) and the N^2 distance matrix is dead.
//
// Per batch b:
//   f       = relu(features[b])            [N,C]
//   r0      = f[0,:]                       [C]
//   gamma_i = max_j exp(f_ij - r0_j) * (f_ij / max_j f_ij)
//   out_i   = gamma_i / ||gamma||_2
//
// Round-2 lesson: hipLaunchCooperativeKernel costs ~25us extra in graph
// replay. This round: ONE regular kernel node. Grid-wide reduction via
// spin-wait on per-block partials:
//   - each block stores (sumsq_partial + 1.0f) with device-scope RELEASE
//     (+1 bias: d_ws poison 0xAA... is a negative float, partial>=1.0 always,
//     so "spin until > 0.5f" terminates regardless of data -> no memset node)
//   - every block stores BEFORE spinning and 64 blocks <= 256 CUs are all
//     immediately resident => no deadlock.
//   - AGENT-scope acquire loads handle cross-XCD L2 non-coherence.

constexpr int kN = 8192;
constexpr int kC = 32;
constexpr int kBlock = 256;
constexpr int kBlocksPerBatch = kN / kBlock;  // 32

__global__ __launch_bounds__(kBlock) void detection_kernel(
    const float* __restrict__ feats, float* __restrict__ out,
    float* __restrict__ partials) {
  const int blk = blockIdx.x;
  const int b = blk >> 5;                      // kBlocksPerBatch = 32
  const int row = (blk & 31) * kBlock + threadIdx.x;
  const float* fb = feats + (size_t)b * kN * kC;

  // Load this row's 32 features (8x float4, contiguous) and row 0's.
  const float4* fr = reinterpret_cast<const float4*>(fb + (size_t)row * kC);
  const float4* f0 = reinterpret_cast<const float4*>(fb);

  float v[kC], r0[kC];
#pragma unroll
  for (int q = 0; q < kC / 4; ++q) {
    float4 t = fr[q];
    v[4 * q + 0] = fmaxf(t.x, 0.f);
    v[4 * q + 1] = fmaxf(t.y, 0.f);
    v[4 * q + 2] = fmaxf(t.z, 0.f);
    v[4 * q + 3] = fmaxf(t.w, 0.f);
    float4 z = f0[q];  // block-uniform, cache-resident
    r0[4 * q + 0] = fmaxf(z.x, 0.f);
    r0[4 * q + 1] = fmaxf(z.y, 0.f);
    r0[4 * q + 2] = fmaxf(z.z, 0.f);
    r0[4 * q + 3] = fmaxf(z.w, 0.f);
  }

  float m = 0.f;
#pragma unroll
  for (int j = 0; j < kC; ++j) m = fmaxf(m, v[j]);
  const float inv_m = 1.0f / m;  // m>0 w.p. 1 - 2^-32 (verified absmax=0)

  float g = 0.f;
#pragma unroll
  for (int j = 0; j < kC; ++j)
    g = fmaxf(g, __expf(v[j] - r0[j]) * (v[j] * inv_m));

  // Block-level sum of g^2: wave shuffle reduce + 4 wave partials in LDS.
  float ss = g * g;
#pragma unroll
  for (int off = 32; off > 0; off >>= 1) ss += __shfl_down(ss, off, 64);
  __shared__ float s_wave[kBlock / 64];
  if ((threadIdx.x & 63) == 0) s_wave[threadIdx.x >> 6] = ss;
  __syncthreads();
  if (threadIdx.x == 0) {
    float total = s_wave[0] + s_wave[1] + s_wave[2] + s_wave[3];
    // +1 bias guarantees stored value >= 1.0 (poison 0xAA.. is negative).
    __hip_atomic_store(&partials[blk], total + 1.0f, __ATOMIC_RELEASE,
                       __HIP_MEMORY_SCOPE_AGENT);
  }

  // Lanes 0..31 of wave 0 each spin on one partial of this batch.
  __shared__ float s_inv;
  if (threadIdx.x < 32) {
    const float* src = &partials[b * kBlocksPerBatch + threadIdx.x];
    float p;
    do {
      p = __hip_atomic_load(src, __ATOMIC_ACQUIRE, __HIP_MEMORY_SCOPE_AGENT);
    } while (p < 0.5f);
    p -= 1.0f;  // remove bias
#pragma unroll
    for (int off = 16; off > 0; off >>= 1) p += __shfl_down(p, off, 32);
    if (threadIdx.x == 0) s_inv = 1.0f / sqrtf(p);
  }
  __syncthreads();

  out[(size_t)b * kN + row] = g * s_inv;
}

extern "C" void kernel_launch(void* const* d_in, const int* in_sizes, int n_in,
                              void* d_out, int out_size, void* d_ws,
                              size_t ws_size, hipStream_t stream) {
  // d_in[0]=coords (unused, dead code), d_in[1]=features [B,N,C] f32,
  // d_in[2]=len_batch (unused).
  const float* feats = (const float*)d_in[1];
  float* out = (float*)d_out;
  float* partials = (float*)d_ws;  // 64 floats; written (with bias) each call

  const int B = out_size / kN;  // 2
  dim3 grid(B * kBlocksPerBatch);  // 64 blocks
  dim3 block(kBlock);

  detection_kernel<<<grid, block, 0, stream>>>(feats, out, partials);
}

// Round 4
// 60.391 us; speedup vs baseline: 1.4856x; 1.0030x over previous
//
#include <hip/hip_runtime.h>

// Reference collapses (verified rounds 1-3, absmax=0.0): nn_idx[0]==0 always
// (self-distance 0 is the first minimum of dist row 0), so
// neighbor_feat = relu(features[b,0,:]) and the N^2 distance matrix is dead.
//
// Per batch b:
//   f       = relu(features[b])            [N,C]
//   r0      = f[0,:]                       [C]
//   gamma_i = max_j exp(f_ij - r0_j) * (f_ij / max_j f_ij)
//   out_i   = gamma_i / ||gamma||_2
//
// Round-2 lesson: cooperative launch costs ~25us extra in graph replay.
// Round-3: single node + grid-wide spin = 60.6us.
// Round-4 experiment: TWO regular nodes, NO memset, NO spin. k1 writes
// gamma to out and (sumsq_partial + 1.0f) per block to d_ws (+1 bias makes
// the value >= 1.0, distinguishable from 0xAA poison — but k2 runs after k1
// via stream order, so bias is just belt-and-braces). k2 reduces the 64
// partials and scales out. Disambiguates spin cost vs node cost.

constexpr int kN = 8192;
constexpr int kC = 32;
constexpr int kBlock = 256;
constexpr int kBlocksPerBatch = kN / kBlock;  // 32

__global__ __launch_bounds__(kBlock) void gamma_kernel(
    const float* __restrict__ feats, float* __restrict__ out,
    float* __restrict__ partials) {
  const int blk = blockIdx.x;
  const int b = blk >> 5;  // kBlocksPerBatch = 32
  const int row = (blk & 31) * kBlock + threadIdx.x;
  const float* fb = feats + (size_t)b * kN * kC;

  const float4* fr = reinterpret_cast<const float4*>(fb + (size_t)row * kC);
  const float4* f0 = reinterpret_cast<const float4*>(fb);

  float v[kC], r0[kC];
#pragma unroll
  for (int q = 0; q < kC / 4; ++q) {
    float4 t = fr[q];
    v[4 * q + 0] = fmaxf(t.x, 0.f);
    v[4 * q + 1] = fmaxf(t.y, 0.f);
    v[4 * q + 2] = fmaxf(t.z, 0.f);
    v[4 * q + 3] = fmaxf(t.w, 0.f);
    float4 z = f0[q];  // block-uniform, cache-resident
    r0[4 * q + 0] = fmaxf(z.x, 0.f);
    r0[4 * q + 1] = fmaxf(z.y, 0.f);
    r0[4 * q + 2] = fmaxf(z.z, 0.f);
    r0[4 * q + 3] = fmaxf(z.w, 0.f);
  }

  float m = 0.f;
#pragma unroll
  for (int j = 0; j < kC; ++j) m = fmaxf(m, v[j]);
  const float inv_m = 1.0f / m;

  float g = 0.f;
#pragma unroll
  for (int j = 0; j < kC; ++j)
    g = fmaxf(g, __expf(v[j] - r0[j]) * (v[j] * inv_m));

  out[(size_t)b * kN + row] = g;  // unnormalized

  // Block-level sum of g^2: wave shuffle reduce + 4 wave partials in LDS.
  float ss = g * g;
#pragma unroll
  for (int off = 32; off > 0; off >>= 1) ss += __shfl_down(ss, off, 64);
  __shared__ float s_wave[kBlock / 64];
  if ((threadIdx.x & 63) == 0) s_wave[threadIdx.x >> 6] = ss;
  __syncthreads();
  if (threadIdx.x == 0)
    partials[blk] = (s_wave[0] + s_wave[1] + s_wave[2] + s_wave[3]) + 1.0f;
}

__global__ __launch_bounds__(kBlock) void norm_kernel(
    float* __restrict__ out, const float* __restrict__ partials) {
  const int blk = blockIdx.x;
  const int b = blk >> 5;
  const int i = blk * kBlock + threadIdx.x;  // 64 blocks cover B*kN exactly

  // Wave 0's lanes 0..31 reduce this batch's 32 partials; broadcast via LDS.
  __shared__ float s_inv;
  if (threadIdx.x < 32) {
    float p = partials[b * kBlocksPerBatch + threadIdx.x] - 1.0f;  // unbias
#pragma unroll
    for (int off = 16; off > 0; off >>= 1) p += __shfl_down(p, off, 32);
    if (threadIdx.x == 0) s_inv = 1.0f / sqrtf(p);
  }
  __syncthreads();

  out[i] *= s_inv;
}

extern "C" void kernel_launch(void* const* d_in, const int* in_sizes, int n_in,
                              void* d_out, int out_size, void* d_ws,
                              size_t ws_size, hipStream_t stream) {
  // d_in[0]=coords (unused, dead code), d_in[1]=features [B,N,C] f32,
  // d_in[2]=len_batch (unused).
  const float* feats = (const float*)d_in[1];
  float* out = (float*)d_out;
  float* partials = (float*)d_ws;  // 64 floats, written by k1 before k2 reads

  const int B = out_size / kN;  // 2
  dim3 grid(B * kBlocksPerBatch);  // 64 blocks
  dim3 block(kBlock);

  gamma_kernel<<<grid, block, 0, stream>>>(feats, out, partials);
  norm_kernel<<<grid, block, 0, stream>>>(out, partials);
}